// Round 1
// baseline (2066.626 us; speedup 1.0000x reference)
//
#include <hip/hip_runtime.h>
#include <math.h>

#define NTRAJ 32
#define TLEN  64
#define BATCH (NTRAJ*TLEN)   // 2048

__device__ __forceinline__ float eluf(float x){ return x > 0.f ? x : expm1f(x); }
__device__ __forceinline__ float sigmf(float x){ return 1.f/(1.f+expf(-x)); }

// ---------------- conv1: NHWC (C=4) input -> 32 channel planes ----------------
// lanes = output pixels; weight reads are wave-uniform -> s_load; acc[32] in VGPRs.
__global__ __launch_bounds__(256) void conv1_kernel(
    const float* __restrict__ in,   // [2048][84][84][4]
    const float* __restrict__ w,    // [3][3][4][32] HWIO
    const float* __restrict__ b,    // [32]
    float* __restrict__ out)        // [32][2048*42*42]
{
    int pos = blockIdx.x*256 + threadIdx.x;      // 3,612,672 exactly
    int n   = pos / (42*42);
    int rem = pos % (42*42);
    int oy  = rem / 42, ox = rem % 42;
    float acc[32];
    #pragma unroll
    for(int o=0;o<32;o++) acc[o] = b[o];
    for(int ky=0; ky<3; ky++){
        int iy = 2*oy + ky;                      // pad_before = 0 (84->42 SAME)
        if(iy >= 84) continue;
        for(int kx=0; kx<3; kx++){
            int ix = 2*ox + kx;
            if(ix >= 84) continue;
            float4 v = *(const float4*)(in + (((n*84 + iy)*84) + ix)*4);
            const float* wq = w + (ky*3 + kx)*128;   // [ci][32]
            #pragma unroll
            for(int o=0;o<32;o++) acc[o] += v.x*wq[o];
            #pragma unroll
            for(int o=0;o<32;o++) acc[o] += v.y*wq[32+o];
            #pragma unroll
            for(int o=0;o<32;o++) acc[o] += v.z*wq[64+o];
            #pragma unroll
            for(int o=0;o<32;o++) acc[o] += v.w*wq[96+o];
        }
    }
    const int NPOS = BATCH*42*42;
    #pragma unroll
    for(int o=0;o<32;o++) out[o*NPOS + pos] = eluf(acc[o]);
}

// ---------------- conv2/3/4: 32 planes -> 32 planes ----------------
template<int IH, int IW, int OH, int OW, int PB>
__global__ __launch_bounds__(256) void convN_kernel(
    const float* __restrict__ in,   // [32][BATCH*IH*IW]
    const float* __restrict__ w,    // [3][3][32][32] HWIO
    const float* __restrict__ b,    // [32]
    float* __restrict__ out)        // [32][BATCH*OH*OW]
{
    const int IPLANE = BATCH*IH*IW;
    const int OPLANE = BATCH*OH*OW;
    int pos = blockIdx.x*256 + threadIdx.x;
    if(pos >= OPLANE) return;       // grids are exact; harmless guard
    int n   = pos / (OH*OW);
    int rem = pos % (OH*OW);
    int oy  = rem / OW, ox = rem % OW;
    float acc[32];
    #pragma unroll
    for(int o=0;o<32;o++) acc[o] = b[o];
    for(int ky=0; ky<3; ky++){
        int iy = 2*oy + ky - PB;
        if(iy < 0 || iy >= IH) continue;
        for(int kx=0; kx<3; kx++){
            int ix = 2*ox + kx - PB;
            if(ix < 0 || ix >= IW) continue;
            const float* ip = in + (n*IH + iy)*IW + ix;
            const float* wp = w + (ky*3 + kx)*1024;  // [ci][32]
            for(int ci=0; ci<32; ci+=4){
                float x0 = ip[(ci+0)*IPLANE];
                float x1 = ip[(ci+1)*IPLANE];
                float x2 = ip[(ci+2)*IPLANE];
                float x3 = ip[(ci+3)*IPLANE];
                const float* wq = wp + ci*32;        // uniform -> s_load
                #pragma unroll
                for(int o=0;o<32;o++) acc[o] += x0*wq[o];
                #pragma unroll
                for(int o=0;o<32;o++) acc[o] += x1*wq[32+o];
                #pragma unroll
                for(int o=0;o<32;o++) acc[o] += x2*wq[64+o];
                #pragma unroll
                for(int o=0;o<32;o++) acc[o] += x3*wq[96+o];
            }
        }
    }
    #pragma unroll
    for(int o=0;o<32;o++) out[o*OPLANE + pos] = eluf(acc[o]);
}

// ---------------- conv4 planes -> A_T[feat=1152][row=2048], row = t*32+n ------
__global__ __launch_bounds__(256) void relayout_kernel(
    const float* __restrict__ p4,   // [32][2048*36]
    float* __restrict__ at)         // [1152][2048]
{
    int i = blockIdx.x*256 + threadIdx.x;   // 2,359,296 exactly
    int f = i >> 11, r = i & 2047;          // write coalesced over r
    int s = f >> 5,  c = f & 31;            // feat = (y*6+x)*32 + c, s = y*6+x
    int t = r >> 5,  n = r & 31;            // r = t*32 + n
    int nt = n*64 + t;
    at[i] = p4[c*(BATCH*36) + nt*36 + s];
}

// ---------------- gate pre-projection: gx[r][1024] = A_T^T @ Wx + b ----------
// lanes = gate columns (coalesced w loads + gx stores); 16 rows/block via s_load.
__global__ __launch_bounds__(256) void gx_gemm_kernel(
    const float* __restrict__ at,   // [1152][2048]
    const float* __restrict__ lw,   // [1408][1024] (rows 0..1151 = Wx)
    const float* __restrict__ lb,   // [1024]
    float* __restrict__ gx)         // [2048][1024], row r = t*32+n
{
    int lane = threadIdx.x & 63;
    int wv   = threadIdx.x >> 6;
    int r0   = blockIdx.x * 16;                    // grid.x = 128
    int oc   = blockIdx.y*256 + wv*64 + lane;      // grid.y = 4
    float acc[16];
    float bias = lb[oc];
    #pragma unroll
    for(int i=0;i<16;i++) acc[i] = bias;
    #pragma unroll 4
    for(int k=0;k<1152;k++){
        float wval = lw[k*1024 + oc];              // coalesced v-load
        const float* ap = at + k*2048 + r0;        // uniform -> s_load_dwordx16
        #pragma unroll
        for(int i=0;i<16;i++) acc[i] += ap[i] * wval;
    }
    #pragma unroll
    for(int i=0;i<16;i++) gx[(r0+i)*1024 + oc] = acc[i];  // coalesced
}

// ---------------- sequential LSTM: 16 WGs x 2 trajectories, no global sync ---
__global__ __launch_bounds__(256) void lstm_kernel(
    const float* __restrict__ gx,   // [2048][1024], row = t*32+n  (bias folded in)
    const float* __restrict__ lw,   // [1408][1024]
    const float* __restrict__ c0,   // [32][256]
    const float* __restrict__ h0,   // [32][256]
    float* __restrict__ feats)      // [2048][256], row = n*64+t
{
    __shared__ float hA[256], hB[256], gb[2][1024];
    const float* wh = lw + 1152*1024;
    int t  = threadIdx.x;
    int nA = blockIdx.x*2, nB = nA + 1;
    hA[t] = h0[nA*256 + t];
    hB[t] = h0[nB*256 + t];
    float cA = c0[nA*256 + t];
    float cB = c0[nB*256 + t];
    __syncthreads();
    for(int st=0; st<64; st++){
        // ---- gates dot-phase: this thread owns columns 4t..4t+3, both trajs
        float aA0=0.f,aA1=0.f,aA2=0.f,aA3=0.f;
        float aB0=0.f,aB1=0.f,aB2=0.f,aB3=0.f;
        #pragma unroll 4
        for(int k4=0;k4<64;k4++){
            float4 ha = *(const float4*)&hA[k4*4];   // LDS broadcast
            float4 hb = *(const float4*)&hB[k4*4];
            const float* wp = wh + (k4*4)*1024 + 4*t;
            {   float4 w4 = *(const float4*)(wp);
                aA0 += ha.x*w4.x; aA1 += ha.x*w4.y; aA2 += ha.x*w4.z; aA3 += ha.x*w4.w;
                aB0 += hb.x*w4.x; aB1 += hb.x*w4.y; aB2 += hb.x*w4.z; aB3 += hb.x*w4.w; }
            {   float4 w4 = *(const float4*)(wp + 1024);
                aA0 += ha.y*w4.x; aA1 += ha.y*w4.y; aA2 += ha.y*w4.z; aA3 += ha.y*w4.w;
                aB0 += hb.y*w4.x; aB1 += hb.y*w4.y; aB2 += hb.y*w4.z; aB3 += hb.y*w4.w; }
            {   float4 w4 = *(const float4*)(wp + 2048);
                aA0 += ha.z*w4.x; aA1 += ha.z*w4.y; aA2 += ha.z*w4.z; aA3 += ha.z*w4.w;
                aB0 += hb.z*w4.x; aB1 += hb.z*w4.y; aB2 += hb.z*w4.z; aB3 += hb.z*w4.w; }
            {   float4 w4 = *(const float4*)(wp + 3072);
                aA0 += ha.w*w4.x; aA1 += ha.w*w4.y; aA2 += ha.w*w4.z; aA3 += ha.w*w4.w;
                aB0 += hb.w*w4.x; aB1 += hb.w*w4.y; aB2 += hb.w*w4.z; aB3 += hb.w*w4.w; }
        }
        float4 gA = *(const float4*)(gx + (st*32 + nA)*1024 + 4*t);
        float4 gB = *(const float4*)(gx + (st*32 + nB)*1024 + 4*t);
        gb[0][4*t+0] = aA0 + gA.x; gb[0][4*t+1] = aA1 + gA.y;
        gb[0][4*t+2] = aA2 + gA.z; gb[0][4*t+3] = aA3 + gA.w;
        gb[1][4*t+0] = aB0 + gB.x; gb[1][4*t+1] = aB1 + gB.y;
        gb[1][4*t+2] = aB2 + gB.z; gb[1][4*t+3] = aB3 + gB.w;
        __syncthreads();
        // ---- update phase: thread owns unit u = t for both trajectories
        {
            float i_ = gb[0][t], j_ = gb[0][t+256], f_ = gb[0][t+512], o_ = gb[0][t+768];
            cA = cA*sigmf(f_+1.f) + sigmf(i_)*tanhf(j_);
            float h = tanhf(cA)*sigmf(o_);
            hA[t] = h;
            feats[(nA*64 + st)*256 + t] = h;
        }
        {
            float i_ = gb[1][t], j_ = gb[1][t+256], f_ = gb[1][t+512], o_ = gb[1][t+768];
            cB = cB*sigmf(f_+1.f) + sigmf(i_)*tanhf(j_);
            float h = tanhf(cB)*sigmf(o_);
            hB[t] = h;
            feats[(nB*64 + st)*256 + t] = h;
        }
        __syncthreads();
    }
}

// ---------------- final FC: logits[p][18] = feats[p] @ fc_w + fc_b ----------
__global__ __launch_bounds__(64) void fc_kernel(
    const float* __restrict__ feats, const float* __restrict__ fw,
    const float* __restrict__ fb,    float* __restrict__ out)
{
    __shared__ float h[256];
    int p = blockIdx.x, t = threadIdx.x;
    *(float4*)&h[t*4] = *(const float4*)(feats + p*256 + t*4);
    __syncthreads();
    if(t < 18){
        float acc = fb[t];
        for(int k=0;k<256;k++) acc += h[k]*fw[k*18 + t];
        out[p*18 + t] = acc;
    }
}

extern "C" void kernel_launch(void* const* d_in, const int* in_sizes, int n_in,
                              void* d_out, int out_size, void* d_ws, size_t ws_size,
                              hipStream_t stream) {
    const float* inp = (const float*)d_in[0];
    const float* w1  = (const float*)d_in[1];  const float* b1 = (const float*)d_in[2];
    const float* w2  = (const float*)d_in[3];  const float* b2 = (const float*)d_in[4];
    const float* w3  = (const float*)d_in[5];  const float* b3 = (const float*)d_in[6];
    const float* w4  = (const float*)d_in[7];  const float* b4 = (const float*)d_in[8];
    const float* lw  = (const float*)d_in[9];  const float* lb = (const float*)d_in[10];
    const float* fw  = (const float*)d_in[11]; const float* fb = (const float*)d_in[12];
    const float* c0  = (const float*)d_in[13]; const float* h0 = (const float*)d_in[14];
    float* out = (float*)d_out;
    float* ws  = (float*)d_ws;

    const size_t n1 = (size_t)32*3612672;   // conv1 out planes
    const size_t n3 = (size_t)32*247808;    // conv3 out planes
    const size_t n4 = (size_t)32*73728;     // conv4 out planes

    float* p1 = ws;
    float* p2 = p1 + n1;                    // conv2 out (28.9M floats)
    float* p3 = ws;                         // reuse p1 region (conv3 reads only p2)
    float* p4 = p3 + n3;
    float* at = p4 + n4;                    // [1152][2048]
    float* gxb   = at  + (size_t)1152*2048; // [2048][1024]
    float* feats = gxb + (size_t)2048*1024; // [2048][256]

    conv1_kernel<<<14112,256,0,stream>>>(inp, w1, b1, p1);
    convN_kernel<42,42,21,21,0><<<3528,256,0,stream>>>(p1, w2, b2, p2);
    convN_kernel<21,21,11,11,1><<<968,256,0,stream>>>(p2, w3, b3, p3);
    convN_kernel<11,11, 6, 6,1><<<288,256,0,stream>>>(p3, w4, b4, p4);
    relayout_kernel<<<9216,256,0,stream>>>(p4, at);
    gx_gemm_kernel<<<dim3(128,4),256,0,stream>>>(at, lw, lb, gxb);
    lstm_kernel<<<16,256,0,stream>>>(gxb, lw, c0, h0, feats);
    fc_kernel<<<2048,64,0,stream>>>(feats, fw, fb, out);
}